// Round 2
// baseline (2703.773 us; speedup 1.0000x reference)
//
#include <hip/hip_runtime.h>
#include <hip/hip_fp16.h>

#define RES 256
#define MS 256
#define ST 512
#define NB 32
#define LUTLEN 262144
#define LUTW 8192   // LUTLEN/32
#define NOUT 32
#define SPB 32      // samples per block (2 pipelined groups of 16)

typedef __attribute__((ext_vector_type(8))) _Float16 half8;
typedef __attribute__((ext_vector_type(4))) float f32x4;

// write-side publish: drain own LDS writes, then raw barrier (NO vmcnt drain --
// in-flight global gather loads stay outstanding across the barrier)
__device__ __forceinline__ void publish_barrier() {
    asm volatile("s_waitcnt lgkmcnt(0)" ::: "memory");
    __builtin_amdgcn_s_barrier();
}

// Pack lut (RES x LUTLEN int32 0/1) into bitmask words: 268MB -> 8MB (L2/L3-resident).
__global__ void pack_lut_kernel(const int* __restrict__ lut, unsigned int* __restrict__ lutp) {
    const long long total = (long long)RES * LUTLEN;
    const int gtid = blockIdx.x * blockDim.x + threadIdx.x;
    const int wave = gtid >> 6;
    const int lane = threadIdx.x & 63;
    const int nwaves = (gridDim.x * blockDim.x) >> 6;
    for (long long base = (long long)wave * 64; base < total; base += (long long)nwaves * 64) {
        int v = lut[base + lane];
        unsigned long long bm = __ballot(v != 0);
        if (lane == 0) {
            unsigned int* p = &lutp[base >> 5];
            p[0] = (unsigned int)bm;
            p[1] = (unsigned int)(bm >> 32);
        }
    }
}

// Pack x (M,S,NB bits) time-major: xp[t*MS + m] = 32 input bits for (sample m, step t).
__global__ void pack_x_kernel(const int* __restrict__ x, unsigned int* __restrict__ xp) {
    const long long total = (long long)MS * ST * NB;
    const int gtid = blockIdx.x * blockDim.x + threadIdx.x;
    const int wave = gtid >> 6;
    const int lane = threadIdx.x & 63;
    const int nwaves = (gridDim.x * blockDim.x) >> 6;
    for (long long base = (long long)wave * 64; base < total; base += (long long)nwaves * 64) {
        int v = x[base + lane];
        unsigned long long bm = __ballot(v != 0);
        if (lane == 0) {
            const int m = (int)(base >> 14);
            const int t0 = ((int)base & 16383) >> 5;
            xp[t0 * MS + m] = (unsigned int)bm;
            xp[(t0 + 1) * MS + m] = (unsigned int)(bm >> 32);
        }
    }
}

// 8 blocks x 512 threads. Block owns 32 samples: group A = first 16, group B = next 16,
// software-pipelined half a step apart so each group's LUT-gather latency hides under
// the other group's ds_read + MFMA chain. Two raw barriers per step, no vmcnt drain.
template<bool LP, bool XP>
__global__ __launch_bounds__(512, 2) void reservoir_kernel(
    const int* __restrict__ xraw,
    const unsigned int* __restrict__ xp,
    const int* __restrict__ lutraw,
    const unsigned int* __restrict__ lutp,
    const int* __restrict__ init_res,
    const int* __restrict__ W,
    const int* __restrict__ primes,
    const int* __restrict__ input_nodes,
    const float* __restrict__ rw,
    const float* __restrict__ rb,
    float* __restrict__ out)
{
    // vA[group][buf][m][k]: (res[k]*primes[k]) f16. Row padded 256->264 halves.
    __shared__ __align__(16) _Float16 vA[2][2][16][264];

    const int tid = threadIdx.x;
    const int lane = tid & 63;
    const int wid = tid >> 6;    // 0..7, each wave owns 2 node-tiles of 16
    const int g = lane >> 4;     // 0..3 (k-group / sample-group)
    const int r = lane & 15;     // A row (sample) & B col (node-within-tile)
    const int m0 = blockIdx.x * SPB;

    const int n0 = wid * 32 + r;
    const int n1 = wid * 32 + 16 + r;

    const _Float16 p0 = (_Float16)(float)primes[n0];
    const _Float16 p1 = (_Float16)(float)primes[n1];
    const _Float16 z  = (_Float16)0.0f;

    int j0 = -1, j1 = -1;
    for (int j = 0; j < NB; ++j) {
        int nn = input_nodes[j];
        if (nn == n0) j0 = j;
        if (nn == n1) j1 = j;
    }

    // B fragments (constant across steps, shared by both groups): 64 VGPRs.
    half8 B0[8], B1[8];
#pragma unroll
    for (int kc = 0; kc < 8; ++kc) {
        const int kb = kc * 32 + g * 8;
        half8 b0, b1;
#pragma unroll
        for (int e = 0; e < 8; ++e) {
            b0[e] = (W[n0 * RES + kb + e] != 0) ? (_Float16)1.0f : z;
            b1[e] = (W[n1 * RES + kb + e] != 0) ? (_Float16)1.0f : z;
        }
        B0[kc] = b0; B1[kc] = b1;
    }

    // init both groups: S(0) = init_res with step-0 scatter, into buf 0
#pragma unroll
    for (int grp = 0; grp < 2; ++grp) {
#pragma unroll
        for (int q = 0; q < 4; ++q) {
            const int m = 4 * g + q;
            const int sm = m0 + grp * 16 + m;
            int b0, b1;
            if (j0 >= 0) b0 = XP ? (int)((xp[sm] >> j0) & 1u) : (xraw[(sm * ST) * NB + j0] != 0);
            else         b0 = (init_res[n0] != 0);
            if (j1 >= 0) b1 = XP ? (int)((xp[sm] >> j1) & 1u) : (xraw[(sm * ST) * NB + j1] != 0);
            else         b1 = (init_res[n1] != 0);
            vA[grp][0][m][n0] = b0 ? p0 : z;
            vA[grp][0][m][n1] = b1 ? p1 : z;
        }
    }
    publish_barrier();

    // COMPUTE(grp,buf,t): ds_read A frags, MFMA (2 parity chains/tile), cvt,
    // ISSUE lut gathers + next-step x words into regs. No waits on the loads here.
    auto COMPUTE = [&](int grp, int buf, int t,
                       unsigned (&w0)[4], unsigned (&w1)[4],
                       unsigned (&s0)[4], unsigned (&s1)[4],
                       unsigned (&xa)[4]) {
        half8 A[8];
#pragma unroll
        for (int kc = 0; kc < 8; ++kc)
            A[kc] = *(const half8*)&vA[grp][buf][r][kc * 32 + g * 8];
        f32x4 c0a = {0.f,0.f,0.f,0.f}, c0b = {0.f,0.f,0.f,0.f};
        f32x4 c1a = {0.f,0.f,0.f,0.f}, c1b = {0.f,0.f,0.f,0.f};
#pragma unroll
        for (int kc = 0; kc < 8; kc += 2) {
            c0a = __builtin_amdgcn_mfma_f32_16x16x32_f16(A[kc],   B0[kc],   c0a, 0, 0, 0);
            c1a = __builtin_amdgcn_mfma_f32_16x16x32_f16(A[kc],   B1[kc],   c1a, 0, 0, 0);
            c0b = __builtin_amdgcn_mfma_f32_16x16x32_f16(A[kc+1], B0[kc+1], c0b, 0, 0, 0);
            c1b = __builtin_amdgcn_mfma_f32_16x16x32_f16(A[kc+1], B1[kc+1], c1b, 0, 0, 0);
        }
#pragma unroll
        for (int q = 0; q < 4; ++q) {
            const unsigned i0 = (unsigned)(c0a[q] + c0b[q]);
            const unsigned i1 = (unsigned)(c1a[q] + c1b[q]);
            if (LP) {
                w0[q] = lutp[n0 * LUTW + (int)(i0 >> 5)];   // raw word; bit-extract deferred
                w1[q] = lutp[n1 * LUTW + (int)(i1 >> 5)];
                s0[q] = i0 & 31u;
                s1[q] = i1 & 31u;
            } else {
                w0[q] = (unsigned)lutraw[(size_t)n0 * LUTLEN + i0];
                w1[q] = (unsigned)lutraw[(size_t)n1 * LUTLEN + i1];
                s0[q] = 0u; s1[q] = 0u;
            }
        }
        if (XP && (t + 1 < ST) && (j0 >= 0 || j1 >= 0)) {
            const uint4 xw = *(const uint4*)&xp[(t + 1) * MS + m0 + grp * 16 + 4 * g];
            xa[0] = xw.x; xa[1] = xw.y; xa[2] = xw.z; xa[3] = xw.w;
        }
    };

    // FINISH(grp,nbuf,t): consume gathered words (vmcnt wait lands here, one phase
    // after issue), fold step-(t+1) input scatter, write S(t+1) to the other buffer.
    auto FINISH = [&](int grp, int nbuf, int t,
                      unsigned (&w0)[4], unsigned (&w1)[4],
                      unsigned (&s0)[4], unsigned (&s1)[4],
                      unsigned (&xa)[4]) {
        const bool last = (t == ST - 1);
#pragma unroll
        for (int q = 0; q < 4; ++q) {
            const int m = 4 * g + q;
            int b0 = LP ? (int)((w0[q] >> s0[q]) & 1u) : (w0[q] != 0u);
            int b1 = LP ? (int)((w1[q] >> s1[q]) & 1u) : (w1[q] != 0u);
            if (!last) {
                const int sm = m0 + grp * 16 + m;
                if (j0 >= 0) b0 = XP ? (int)((xa[q] >> j0) & 1u)
                                     : (xraw[(sm * ST + (t + 1)) * NB + j0] != 0);
                if (j1 >= 0) b1 = XP ? (int)((xa[q] >> j1) & 1u)
                                     : (xraw[(sm * ST + (t + 1)) * NB + j1] != 0);
            }
            vA[grp][nbuf][m][n0] = b0 ? p0 : z;
            vA[grp][nbuf][m][n1] = b1 ? p1 : z;
        }
    };

    unsigned wA0[4], wA1[4], sA0[4], sA1[4], xaA[4];
    unsigned wB0[4], wB1[4], sB0[4], sB1[4], xaB[4];

    COMPUTE(0, 0, 0, wA0, wA1, sA0, sA1, xaA);      // prime the pipeline (group A)
#pragma unroll 1
    for (int t = 0; t < ST - 1; ++t) {
        const int cb = t & 1, nb = cb ^ 1;
        COMPUTE(1, cb, t, wB0, wB1, sB0, sB1, xaB); // B compute hides A's gathers
        FINISH (0, nb, t, wA0, wA1, sA0, sA1, xaA);
        publish_barrier();                          // S_A(t+1) published
        COMPUTE(0, nb, t + 1, wA0, wA1, sA0, sA1, xaA); // A compute hides B's gathers
        FINISH (1, nb, t, wB0, wB1, sB0, sB1, xaB);
        publish_barrier();                          // S_B(t+1) published
    }
    // epilogue: t = ST-1 (cb=1, nb=0), no next-step scatter, no further COMPUTE(A)
    COMPUTE(1, 1, ST - 1, wB0, wB1, sB0, sB1, xaB);
    FINISH (0, 0, ST - 1, wA0, wA1, sA0, sA1, xaA);
    publish_barrier();
    FINISH (1, 0, ST - 1, wB0, wB1, sB0, sB1, xaB);
    publish_barrier();

    // readout: final states of both groups are in buf 0; state bit = (vA != 0)
    {
        const int mm = tid >> 5;   // 0..15
        const int o  = tid & 31;
#pragma unroll
        for (int grp = 0; grp < 2; ++grp) {
            float acc = rb[o];
            for (int n = 0; n < RES; ++n) {
                if (vA[grp][0][mm][n] != z) acc += rw[o * RES + n];
            }
            out[(m0 + grp * 16 + mm) * NOUT + o] = acc;
        }
    }
}

extern "C" void kernel_launch(void* const* d_in, const int* in_sizes, int n_in,
                              void* d_out, int out_size, void* d_ws, size_t ws_size,
                              hipStream_t stream) {
    const int* x           = (const int*)d_in[0];
    const int* lut         = (const int*)d_in[1];
    const int* init_res    = (const int*)d_in[2];
    const int* W           = (const int*)d_in[3];
    const int* primes      = (const int*)d_in[4];
    const int* input_nodes = (const int*)d_in[5];
    const float* rw        = (const float*)d_in[6];
    const float* rb        = (const float*)d_in[7];
    float* out = (float*)d_out;

    const size_t lutp_bytes = (size_t)RES * LUTW * sizeof(unsigned int); // 8 MB
    const size_t xp_bytes   = (size_t)ST * MS * sizeof(unsigned int);    // 512 KB

    unsigned int* lutp = nullptr;
    unsigned int* xp = nullptr;
    bool use_lp = false, use_xp = false;
    unsigned char* ws = (unsigned char*)d_ws;
    if (ws_size >= lutp_bytes + xp_bytes) {
        lutp = (unsigned int*)ws;
        xp = (unsigned int*)(ws + lutp_bytes);
        use_lp = use_xp = true;
    } else if (ws_size >= xp_bytes) {
        xp = (unsigned int*)ws;
        use_xp = true;
    }

    if (use_lp) hipLaunchKernelGGL(pack_lut_kernel, dim3(256), dim3(256), 0, stream, lut, lutp);
    if (use_xp) hipLaunchKernelGGL(pack_x_kernel, dim3(64), dim3(256), 0, stream, x, xp);

    const int nblk = MS / SPB;  // 8
    if (use_lp)
        hipLaunchKernelGGL((reservoir_kernel<true, true>), dim3(nblk), dim3(512), 0, stream,
                           x, xp, lut, lutp, init_res, W, primes, input_nodes, rw, rb, out);
    else if (use_xp)
        hipLaunchKernelGGL((reservoir_kernel<false, true>), dim3(nblk), dim3(512), 0, stream,
                           x, xp, lut, lutp, init_res, W, primes, input_nodes, rw, rb, out);
    else
        hipLaunchKernelGGL((reservoir_kernel<false, false>), dim3(nblk), dim3(512), 0, stream,
                           x, xp, lut, lutp, init_res, W, primes, input_nodes, rw, rb, out);
}

// Round 3
// 522.014 us; speedup vs baseline: 5.1795x; 5.1795x over previous
//
#include <hip/hip_runtime.h>
#include <hip/hip_fp16.h>

#define RES 256
#define MS 256
#define ST 512
#define NB 32
#define LUTLEN 262144
#define LUTW 8192   // LUTLEN/32
#define NOUT 32
#define SPBR 2      // samples per block
#define NBLK (MS / SPBR)  // 128 blocks -> 128 CUs, 512 gather-lines/CU/step

typedef __attribute__((ext_vector_type(8))) _Float16 half8;
typedef __attribute__((ext_vector_type(4))) float f32x4;

// Per-lane LUT bit-pack: each thread packs 32 consecutive int32 0/1 entries
// (8 x int4 = 128B) into one u32. 268MB -> 8MB (L2/L3-resident afterwards).
__global__ __launch_bounds__(256) void pack_lut_kernel(const int* __restrict__ lut,
                                                       unsigned* __restrict__ lutp) {
    const int total = RES * LUTW;  // 2,097,152 output words
    int w = blockIdx.x * blockDim.x + threadIdx.x;
    const int stride = gridDim.x * blockDim.x;
    for (; w < total; w += stride) {
        const int4* p = (const int4*)(lut + (size_t)w * 32);
        unsigned word = 0u;
#pragma unroll
        for (int c = 0; c < 8; ++c) {
            const int4 v = p[c];
            word |= (v.x != 0 ? 1u : 0u) << (4 * c + 0);
            word |= (v.y != 0 ? 1u : 0u) << (4 * c + 1);
            word |= (v.z != 0 ? 1u : 0u) << (4 * c + 2);
            word |= (v.w != 0 ? 1u : 0u) << (4 * c + 3);
        }
        lutp[w] = word;
    }
}

// Per-lane x pack, time-major output: xp[t*MS + m] = 32 input bits of (m, t).
// Input x[m][t][0..31] is contiguous -> word w = m*ST + t reads lut-style 128B.
__global__ __launch_bounds__(256) void pack_x_kernel(const int* __restrict__ x,
                                                     unsigned* __restrict__ xp) {
    const int total = MS * ST;  // 131,072 words
    int w = blockIdx.x * blockDim.x + threadIdx.x;
    const int stride = gridDim.x * blockDim.x;
    for (; w < total; w += stride) {
        const int4* p = (const int4*)(x + (size_t)w * 32);
        unsigned word = 0u;
#pragma unroll
        for (int c = 0; c < 8; ++c) {
            const int4 v = p[c];
            word |= (v.x != 0 ? 1u : 0u) << (4 * c + 0);
            word |= (v.y != 0 ? 1u : 0u) << (4 * c + 1);
            word |= (v.z != 0 ? 1u : 0u) << (4 * c + 2);
            word |= (v.w != 0 ? 1u : 0u) << (4 * c + 3);
        }
        const int m = w >> 9;       // / ST
        const int t = w & (ST - 1);
        xp[t * MS + m] = word;
    }
}

// 128 blocks x 512 threads; block owns SPBR=2 samples (A rows 0..1; rows 2..15 zero).
// Per step: state_idx = (res*primes) @ W^T via 16x16x32 f16 MFMA (exact), LUT bit
// gather from C regs (only the 16 g==0 lanes own real rows), next-step scatter folded
// into the LDS write, one __syncthreads per step. Round-1-verified structure.
template<bool LP, bool XP>
__global__ __launch_bounds__(512) void reservoir_kernel(
    const int* __restrict__ xraw,
    const unsigned* __restrict__ xp,
    const int* __restrict__ lutraw,
    const unsigned* __restrict__ lutp,
    const int* __restrict__ init_res,
    const int* __restrict__ W,
    const int* __restrict__ primes,
    const int* __restrict__ input_nodes,
    const float* __restrict__ rw,
    const float* __restrict__ rb,
    float* __restrict__ out)
{
    // vA[buf][m][k]: (res[k]*primes[k]) f16. Row padded 256->264 halves.
    __shared__ __align__(16) _Float16 vA[2][16][264];

    const int tid = threadIdx.x;
    const int lane = tid & 63;
    const int wid = tid >> 6;    // 0..7, each wave owns 2 node-tiles of 16
    const int g = lane >> 4;     // 0..3 (k-group / C row-group)
    const int r = lane & 15;     // A row & B col (node-within-tile)
    const int m0 = blockIdx.x * SPBR;

    const int n0 = wid * 32 + r;
    const int n1 = wid * 32 + 16 + r;

    const _Float16 p0 = (_Float16)(float)primes[n0];
    const _Float16 p1 = (_Float16)(float)primes[n1];
    const _Float16 z  = (_Float16)0.0f;

    int j0 = -1, j1 = -1;
    for (int j = 0; j < NB; ++j) {
        int nn = input_nodes[j];
        if (nn == n0) j0 = j;
        if (nn == n1) j1 = j;
    }

    // B fragments (constant across steps): B[k][j] = W[node j][k], 0/1 f16. 64 VGPRs.
    half8 B0[8], B1[8];
#pragma unroll
    for (int kc = 0; kc < 8; ++kc) {
        const int kb = kc * 32 + g * 8;
        const int4* w0p = (const int4*)(W + n0 * RES + kb);
        const int4* w1p = (const int4*)(W + n1 * RES + kb);
        const int4 wa = w0p[0], wb = w0p[1], wc = w1p[0], wd = w1p[1];
        half8 b0, b1;
        b0[0] = wa.x != 0 ? (_Float16)1.0f : z;  b0[1] = wa.y != 0 ? (_Float16)1.0f : z;
        b0[2] = wa.z != 0 ? (_Float16)1.0f : z;  b0[3] = wa.w != 0 ? (_Float16)1.0f : z;
        b0[4] = wb.x != 0 ? (_Float16)1.0f : z;  b0[5] = wb.y != 0 ? (_Float16)1.0f : z;
        b0[6] = wb.z != 0 ? (_Float16)1.0f : z;  b0[7] = wb.w != 0 ? (_Float16)1.0f : z;
        b1[0] = wc.x != 0 ? (_Float16)1.0f : z;  b1[1] = wc.y != 0 ? (_Float16)1.0f : z;
        b1[2] = wc.z != 0 ? (_Float16)1.0f : z;  b1[3] = wc.w != 0 ? (_Float16)1.0f : z;
        b1[4] = wd.x != 0 ? (_Float16)1.0f : z;  b1[5] = wd.y != 0 ? (_Float16)1.0f : z;
        b1[6] = wd.z != 0 ? (_Float16)1.0f : z;  b1[7] = wd.w != 0 ? (_Float16)1.0f : z;
        B0[kc] = b0; B1[kc] = b1;
    }

    // zero both buffers (rows >= SPBR must stay zero forever)
    {
        unsigned* vz = (unsigned*)&vA[0][0][0];
        const int nwords = 2 * 16 * 264 / 2;  // 4224 u32 words
        for (int i = tid; i < nwords; i += 512) vz[i] = 0u;
    }
    __syncthreads();

    // init: S(0) = init_res with step-0 scatter, rows 0..SPBR-1 of buf 0
    if (g == 0) {
#pragma unroll
        for (int q = 0; q < SPBR; ++q) {
            const int sm = m0 + q;
            int b0, b1;
            if (j0 >= 0) b0 = XP ? (int)((xp[sm] >> j0) & 1u) : (xraw[(sm * ST) * NB + j0] != 0);
            else         b0 = (init_res[n0] != 0);
            if (j1 >= 0) b1 = XP ? (int)((xp[sm] >> j1) & 1u) : (xraw[(sm * ST) * NB + j1] != 0);
            else         b1 = (init_res[n1] != 0);
            vA[0][q][n0] = b0 ? p0 : z;
            vA[0][q][n1] = b1 ? p1 : z;
        }
    }
    __syncthreads();

#pragma unroll 1
    for (int t = 0; t < ST; ++t) {
        const int cur = t & 1, nxt = cur ^ 1;
        half8 A[8];
#pragma unroll
        for (int kc = 0; kc < 8; ++kc)
            A[kc] = *(const half8*)&vA[cur][r][kc * 32 + g * 8];
        f32x4 c0a = {0.f,0.f,0.f,0.f}, c0b = {0.f,0.f,0.f,0.f};
        f32x4 c1a = {0.f,0.f,0.f,0.f}, c1b = {0.f,0.f,0.f,0.f};
#pragma unroll
        for (int kc = 0; kc < 8; kc += 2) {
            c0a = __builtin_amdgcn_mfma_f32_16x16x32_f16(A[kc],   B0[kc],   c0a, 0, 0, 0);
            c1a = __builtin_amdgcn_mfma_f32_16x16x32_f16(A[kc],   B1[kc],   c1a, 0, 0, 0);
            c0b = __builtin_amdgcn_mfma_f32_16x16x32_f16(A[kc+1], B0[kc+1], c0b, 0, 0, 0);
            c1b = __builtin_amdgcn_mfma_f32_16x16x32_f16(A[kc+1], B1[kc+1], c1b, 0, 0, 0);
        }

        // only g==0 lanes hold real C rows (samples 0..SPBR-1)
        if (g == 0) {
            const bool last = (t == ST - 1);
            unsigned w0[SPBR], w1[SPBR], s0[SPBR], s1[SPBR];
#pragma unroll
            for (int q = 0; q < SPBR; ++q) {
                const unsigned i0 = (unsigned)(c0a[q] + c0b[q]);
                const unsigned i1 = (unsigned)(c1a[q] + c1b[q]);
                if (LP) {
                    w0[q] = lutp[n0 * LUTW + (int)(i0 >> 5)];
                    w1[q] = lutp[n1 * LUTW + (int)(i1 >> 5)];
                    s0[q] = i0 & 31u; s1[q] = i1 & 31u;
                } else {
                    w0[q] = (unsigned)lutraw[(size_t)n0 * LUTLEN + i0];
                    w1[q] = (unsigned)lutraw[(size_t)n1 * LUTLEN + i1];
                    s0[q] = 0u; s1[q] = 0u;
                }
            }
            uint2 xw2 = {0u, 0u};
            if (XP && !last) xw2 = *(const uint2*)&xp[(t + 1) * MS + m0];
#pragma unroll
            for (int q = 0; q < SPBR; ++q) {
                int b0 = LP ? (int)((w0[q] >> s0[q]) & 1u) : (w0[q] != 0u);
                int b1 = LP ? (int)((w1[q] >> s1[q]) & 1u) : (w1[q] != 0u);
                if (!last) {
                    const int sm = m0 + q;
                    const unsigned xa = q == 0 ? xw2.x : xw2.y;
                    if (j0 >= 0) b0 = XP ? (int)((xa >> j0) & 1u)
                                         : (xraw[(sm * ST + (t + 1)) * NB + j0] != 0);
                    if (j1 >= 0) b1 = XP ? (int)((xa >> j1) & 1u)
                                         : (xraw[(sm * ST + (t + 1)) * NB + j1] != 0);
                }
                vA[nxt][q][n0] = b0 ? p0 : z;
                vA[nxt][q][n1] = b1 ? p1 : z;
            }
        }
        __syncthreads();
    }

    // readout: final state in buf 0 (512 toggles), rows 0..SPBR-1
    if (tid < SPBR * NOUT) {
        const int m = tid >> 5;
        const int o = tid & 31;
        float acc = rb[o];
        for (int n = 0; n < RES; ++n) {
            if (vA[0][m][n] != z) acc += rw[o * RES + n];
        }
        out[(m0 + m) * NOUT + o] = acc;
    }
}

extern "C" void kernel_launch(void* const* d_in, const int* in_sizes, int n_in,
                              void* d_out, int out_size, void* d_ws, size_t ws_size,
                              hipStream_t stream) {
    const int* x           = (const int*)d_in[0];
    const int* lut         = (const int*)d_in[1];
    const int* init_res    = (const int*)d_in[2];
    const int* W           = (const int*)d_in[3];
    const int* primes      = (const int*)d_in[4];
    const int* input_nodes = (const int*)d_in[5];
    const float* rw        = (const float*)d_in[6];
    const float* rb        = (const float*)d_in[7];
    float* out = (float*)d_out;

    const size_t lutp_bytes = (size_t)RES * LUTW * sizeof(unsigned); // 8 MB
    const size_t xp_bytes   = (size_t)ST * MS * sizeof(unsigned);    // 512 KB

    unsigned* lutp = nullptr;
    unsigned* xp = nullptr;
    bool use_lp = false, use_xp = false;
    unsigned char* ws = (unsigned char*)d_ws;
    if (ws_size >= lutp_bytes + xp_bytes) {
        lutp = (unsigned*)ws;
        xp = (unsigned*)(ws + lutp_bytes);
        use_lp = use_xp = true;
    } else if (ws_size >= xp_bytes) {
        xp = (unsigned*)ws;
        use_xp = true;
    }

    if (use_lp) hipLaunchKernelGGL(pack_lut_kernel, dim3(4096), dim3(256), 0, stream, lut, lutp);
    if (use_xp) hipLaunchKernelGGL(pack_x_kernel, dim3(512), dim3(256), 0, stream, x, xp);

    if (use_lp)
        hipLaunchKernelGGL((reservoir_kernel<true, true>), dim3(NBLK), dim3(512), 0, stream,
                           x, xp, lut, lutp, init_res, W, primes, input_nodes, rw, rb, out);
    else if (use_xp)
        hipLaunchKernelGGL((reservoir_kernel<false, true>), dim3(NBLK), dim3(512), 0, stream,
                           x, xp, lut, lutp, init_res, W, primes, input_nodes, rw, rb, out);
    else
        hipLaunchKernelGGL((reservoir_kernel<false, false>), dim3(NBLK), dim3(512), 0, stream,
                           x, xp, lut, lutp, init_res, W, primes, input_nodes, rw, rb, out);
}

// Round 4
// 410.454 us; speedup vs baseline: 6.5873x; 1.2718x over previous
//
#include <hip/hip_runtime.h>
#include <hip/hip_fp16.h>

#define RES 256
#define MS 256
#define ST 512
#define NB 32
#define LUTLEN 262144
#define LUTW 8192      // LUTLEN/32
#define NOUT 32
#define NBLK 256       // 1 sample per block

typedef __attribute__((ext_vector_type(8))) _Float16 half8;
typedef __attribute__((ext_vector_type(4))) float f32x4;

// ---- Pass 1: per-node reachable-size + exclusive prefix sum (1 block, 256 thr) ----
// off[n] = word offset of node n's compact LUT row; off[256] = total words.
__global__ __launch_bounds__(256) void lut_offsets_kernel(const int* __restrict__ W,
                                                          const int* __restrict__ primes,
                                                          int* __restrict__ off) {
    __shared__ int s[RES];
    const int n = threadIdx.x;
    int maxsum = 0;
    for (int k = 0; k < RES; ++k)
        maxsum += (W[n * RES + k] != 0) ? primes[k] : 0;
    int nw = (maxsum >> 5) + 1;           // words needed for indices 0..maxsum
    s[n] = nw;
    __syncthreads();
    // Hillis-Steele inclusive scan
    for (int d = 1; d < RES; d <<= 1) {
        int v = (n >= d) ? s[n - d] : 0;
        __syncthreads();
        s[n] += v;
        __syncthreads();
    }
    off[n] = s[n] - nw;                   // exclusive
    if (n == RES - 1) off[RES] = s[n];
}

// ---- Pass 2: compact bit-pack. Block b = node b; pack words 0..nw-1. ----
__global__ __launch_bounds__(512) void pack_lut2_kernel(const int* __restrict__ lut,
                                                        const int* __restrict__ off,
                                                        unsigned* __restrict__ lutp) {
    const int n = blockIdx.x;
    const int o = off[n];
    const int nw = off[n + 1] - o;
    const int* src = lut + (size_t)n * LUTLEN;
    for (int w = threadIdx.x; w < nw; w += blockDim.x) {
        const int4* p = (const int4*)(src + (size_t)w * 32);
        unsigned word = 0u;
#pragma unroll
        for (int c = 0; c < 8; ++c) {
            const int4 v = p[c];
            word |= (v.x != 0 ? 1u : 0u) << (4 * c + 0);
            word |= (v.y != 0 ? 1u : 0u) << (4 * c + 1);
            word |= (v.z != 0 ? 1u : 0u) << (4 * c + 2);
            word |= (v.w != 0 ? 1u : 0u) << (4 * c + 3);
        }
        lutp[o + w] = word;
    }
}

// Pack x time-major: xp[t*MS + m] = 32 input bits of (m, t).
__global__ __launch_bounds__(256) void pack_x_kernel(const int* __restrict__ x,
                                                     unsigned* __restrict__ xp) {
    const int total = MS * ST;
    int w = blockIdx.x * blockDim.x + threadIdx.x;
    const int stride = gridDim.x * blockDim.x;
    for (; w < total; w += stride) {
        const int4* p = (const int4*)(x + (size_t)w * 32);
        unsigned word = 0u;
#pragma unroll
        for (int c = 0; c < 8; ++c) {
            const int4 v = p[c];
            word |= (v.x != 0 ? 1u : 0u) << (4 * c + 0);
            word |= (v.y != 0 ? 1u : 0u) << (4 * c + 1);
            word |= (v.z != 0 ? 1u : 0u) << (4 * c + 2);
            word |= (v.w != 0 ? 1u : 0u) << (4 * c + 3);
        }
        const int m = w >> 9;
        const int t = w & (ST - 1);
        xp[t * MS + m] = word;
    }
}

// 256 blocks x 512 threads; block owns ONE sample. State row (res*primes, f16) lives
// in a single 512B LDS row; all 16 lanes of a k-group broadcast-read the same 16B
// (A rows 1..15 are garbage -> C rows 1..15 unused). Compact L2-resident LUT.
template<bool LP, bool XP>
__global__ __launch_bounds__(512) void reservoir_kernel(
    const int* __restrict__ xraw,
    const unsigned* __restrict__ xp,
    const int* __restrict__ lutraw,
    const unsigned* __restrict__ lutp,
    const int* __restrict__ off,
    const int* __restrict__ init_res,
    const int* __restrict__ W,
    const int* __restrict__ primes,
    const int* __restrict__ input_nodes,
    const float* __restrict__ rw,
    const float* __restrict__ rb,
    float* __restrict__ out)
{
    __shared__ __align__(16) _Float16 vArow[2][264];  // double-buffered state row
    __shared__ unsigned xw_lds[ST];                   // this sample's 512 x-words

    const int tid = threadIdx.x;
    const int lane = tid & 63;
    const int wid = tid >> 6;    // 0..7, wave owns 2 node-tiles of 16
    const int g = lane >> 4;     // 0..3 (k-group)
    const int r = lane & 15;     // B col (node-within-tile); A row for r==0 only
    const int m0 = blockIdx.x;   // the sample

    const int n0 = wid * 32 + r;
    const int n1 = wid * 32 + 16 + r;

    const _Float16 p0 = (_Float16)(float)primes[n0];
    const _Float16 p1 = (_Float16)(float)primes[n1];
    const _Float16 z  = (_Float16)0.0f;

    const int off0 = LP ? off[n0] : 0;
    const int off1 = LP ? off[n1] : 0;

    int j0 = -1, j1 = -1;
    for (int j = 0; j < NB; ++j) {
        int nn = input_nodes[j];
        if (nn == n0) j0 = j;
        if (nn == n1) j1 = j;
    }

    // B fragments (constant): B[k][col] = W[node col][k], 0/1 f16. 64 VGPRs.
    half8 B0[8], B1[8];
#pragma unroll
    for (int kc = 0; kc < 8; ++kc) {
        const int kb = kc * 32 + g * 8;
        const int4* w0p = (const int4*)(W + n0 * RES + kb);
        const int4* w1p = (const int4*)(W + n1 * RES + kb);
        const int4 wa = w0p[0], wb = w0p[1], wc = w1p[0], wd = w1p[1];
        half8 b0, b1;
        b0[0] = wa.x != 0 ? (_Float16)1.0f : z;  b0[1] = wa.y != 0 ? (_Float16)1.0f : z;
        b0[2] = wa.z != 0 ? (_Float16)1.0f : z;  b0[3] = wa.w != 0 ? (_Float16)1.0f : z;
        b0[4] = wb.x != 0 ? (_Float16)1.0f : z;  b0[5] = wb.y != 0 ? (_Float16)1.0f : z;
        b0[6] = wb.z != 0 ? (_Float16)1.0f : z;  b0[7] = wb.w != 0 ? (_Float16)1.0f : z;
        b1[0] = wc.x != 0 ? (_Float16)1.0f : z;  b1[1] = wc.y != 0 ? (_Float16)1.0f : z;
        b1[2] = wc.z != 0 ? (_Float16)1.0f : z;  b1[3] = wc.w != 0 ? (_Float16)1.0f : z;
        b1[4] = wd.x != 0 ? (_Float16)1.0f : z;  b1[5] = wd.y != 0 ? (_Float16)1.0f : z;
        b1[6] = wd.z != 0 ? (_Float16)1.0f : z;  b1[7] = wd.w != 0 ? (_Float16)1.0f : z;
        B0[kc] = b0; B1[kc] = b1;
    }

    // stage this sample's x words (time-major -> strided, once) into LDS
    if (XP) xw_lds[tid] = xp[tid * MS + m0];

    // init: S(0) = init_res with step-0 scatter (g==0 lanes cover all 256 nodes)
    if (g == 0) {
        int b0, b1;
        if (XP) {
            // xw_lds not synced yet; read xp directly for t=0
            const unsigned xa = xp[m0];
            b0 = (j0 >= 0) ? (int)((xa >> j0) & 1u) : (init_res[n0] != 0);
            b1 = (j1 >= 0) ? (int)((xa >> j1) & 1u) : (init_res[n1] != 0);
        } else {
            b0 = (j0 >= 0) ? (xraw[(m0 * ST) * NB + j0] != 0) : (init_res[n0] != 0);
            b1 = (j1 >= 0) ? (xraw[(m0 * ST) * NB + j1] != 0) : (init_res[n1] != 0);
        }
        vArow[0][n0] = b0 ? p0 : z;
        vArow[0][n1] = b1 ? p1 : z;
    }
    __syncthreads();

#pragma unroll 1
    for (int t = 0; t < ST; ++t) {
        const int cur = t & 1, nxt = cur ^ 1;
        half8 A[8];
#pragma unroll
        for (int kc = 0; kc < 8; ++kc)
            A[kc] = *(const half8*)&vArow[cur][kc * 32 + g * 8];  // broadcast in group
        f32x4 c0a = {0.f,0.f,0.f,0.f}, c0b = {0.f,0.f,0.f,0.f};
        f32x4 c1a = {0.f,0.f,0.f,0.f}, c1b = {0.f,0.f,0.f,0.f};
#pragma unroll
        for (int kc = 0; kc < 8; kc += 2) {
            c0a = __builtin_amdgcn_mfma_f32_16x16x32_f16(A[kc],   B0[kc],   c0a, 0, 0, 0);
            c1a = __builtin_amdgcn_mfma_f32_16x16x32_f16(A[kc],   B1[kc],   c1a, 0, 0, 0);
            c0b = __builtin_amdgcn_mfma_f32_16x16x32_f16(A[kc+1], B0[kc+1], c0b, 0, 0, 0);
            c1b = __builtin_amdgcn_mfma_f32_16x16x32_f16(A[kc+1], B1[kc+1], c1b, 0, 0, 0);
        }

        if (g == 0) {
            const bool last = (t == ST - 1);
            const unsigned i0 = (unsigned)(c0a[0] + c0b[0]);
            const unsigned i1 = (unsigned)(c1a[0] + c1b[0]);
            unsigned w0, w1, s0, s1;
            if (LP) {
                w0 = lutp[off0 + (int)(i0 >> 5)];
                w1 = lutp[off1 + (int)(i1 >> 5)];
                s0 = i0 & 31u; s1 = i1 & 31u;
            } else {
                w0 = (unsigned)lutraw[(size_t)n0 * LUTLEN + i0];
                w1 = (unsigned)lutraw[(size_t)n1 * LUTLEN + i1];
                s0 = 0u; s1 = 0u;
            }
            int b0 = LP ? (int)((w0 >> s0) & 1u) : (w0 != 0u);
            int b1 = LP ? (int)((w1 >> s1) & 1u) : (w1 != 0u);
            if (!last) {
                if (XP) {
                    const unsigned xa = xw_lds[t + 1];
                    if (j0 >= 0) b0 = (int)((xa >> j0) & 1u);
                    if (j1 >= 0) b1 = (int)((xa >> j1) & 1u);
                } else {
                    if (j0 >= 0) b0 = (xraw[(m0 * ST + (t + 1)) * NB + j0] != 0);
                    if (j1 >= 0) b1 = (xraw[(m0 * ST + (t + 1)) * NB + j1] != 0);
                }
            }
            vArow[nxt][n0] = b0 ? p0 : z;
            vArow[nxt][n1] = b1 ? p1 : z;
        }
        __syncthreads();
    }

    // readout: final state S(512) is in buf 0
    if (tid < NOUT) {
        const int o = tid;
        float acc = rb[o];
        for (int n = 0; n < RES; ++n) {
            if (vArow[0][n] != z) acc += rw[o * RES + n];
        }
        out[m0 * NOUT + o] = acc;
    }
}

extern "C" void kernel_launch(void* const* d_in, const int* in_sizes, int n_in,
                              void* d_out, int out_size, void* d_ws, size_t ws_size,
                              hipStream_t stream) {
    const int* x           = (const int*)d_in[0];
    const int* lut         = (const int*)d_in[1];
    const int* init_res    = (const int*)d_in[2];
    const int* W           = (const int*)d_in[3];
    const int* primes      = (const int*)d_in[4];
    const int* input_nodes = (const int*)d_in[5];
    const float* rw        = (const float*)d_in[6];
    const float* rb        = (const float*)d_in[7];
    float* out = (float*)d_out;

    const size_t lutp_bytes = (size_t)RES * LUTW * sizeof(unsigned); // 8 MB cap
    const size_t xp_bytes   = (size_t)ST * MS * sizeof(unsigned);    // 512 KB
    const size_t off_bytes  = (RES + 1) * sizeof(int);               // 1028 B

    unsigned* lutp = nullptr;
    unsigned* xp = nullptr;
    int* off = nullptr;
    bool use_lp = false, use_xp = false;
    unsigned char* ws = (unsigned char*)d_ws;
    if (ws_size >= lutp_bytes + xp_bytes + 256 + off_bytes) {
        lutp = (unsigned*)ws;
        xp = (unsigned*)(ws + lutp_bytes);
        off = (int*)(ws + lutp_bytes + xp_bytes);
        use_lp = use_xp = true;
    } else if (ws_size >= xp_bytes) {
        xp = (unsigned*)ws;
        use_xp = true;
    }

    if (use_lp) {
        hipLaunchKernelGGL(lut_offsets_kernel, dim3(1), dim3(256), 0, stream, W, primes, off);
        hipLaunchKernelGGL(pack_lut2_kernel, dim3(RES), dim3(512), 0, stream, lut, off, lutp);
    }
    if (use_xp) hipLaunchKernelGGL(pack_x_kernel, dim3(512), dim3(256), 0, stream, x, xp);

    if (use_lp)
        hipLaunchKernelGGL((reservoir_kernel<true, true>), dim3(NBLK), dim3(512), 0, stream,
                           x, xp, lut, lutp, off, init_res, W, primes, input_nodes, rw, rb, out);
    else if (use_xp)
        hipLaunchKernelGGL((reservoir_kernel<false, true>), dim3(NBLK), dim3(512), 0, stream,
                           x, xp, lut, lutp, off, init_res, W, primes, input_nodes, rw, rb, out);
    else
        hipLaunchKernelGGL((reservoir_kernel<false, false>), dim3(NBLK), dim3(512), 0, stream,
                           x, xp, lut, lutp, off, init_res, W, primes, input_nodes, rw, rb, out);
}